// Round 2
// baseline (1065.487 us; speedup 1.0000x reference)
//
#include <hip/hip_runtime.h>
#include <hip/hip_bf16.h>

#define N_STORE 100000
#define N_DEPT  20000
#define F_IN    128
#define NTOT    (N_DEPT + 2 * N_STORE)   // combined CSR arena (rel0 | rel1 | rel2)

using u16    = unsigned short;
using bf16x8 = __attribute__((ext_vector_type(8))) __bf16;
using f32x4  = __attribute__((ext_vector_type(4))) float;

__device__ __forceinline__ float b2f(u16 x) {
    unsigned u = ((unsigned)x) << 16;
    return __builtin_bit_cast(float, u);
}
__device__ __forceinline__ u16 f2b(float f) {
    unsigned u = __builtin_bit_cast(unsigned, f);
    u += 0x7FFFu + ((u >> 16) & 1u);   // round-to-nearest-even
    return (u16)(u >> 16);
}

// ---------------- fused CSR build, 3 relations in one arena ----------------
// arena layout: rel0 (store->dept, n=N_DEPT) | rel1 (dept->store, n=N_STORE) | rel2 (n=N_STORE)
// srcs_all is one 3E array; offs values are global indices into it.
__global__ void k_zeroi(int* p, int n) {
    int i = blockIdx.x * 256 + threadIdx.x;
    if (i < n) p[i] = 0;
}

__global__ void k_hist3(const int* __restrict__ e0, const int* __restrict__ e1,
                        const int* __restrict__ e2, int E, int* __restrict__ counts) {
    int by = blockIdx.y;
    const int* e = (by == 0) ? e0 : (by == 1) ? e1 : e2;
    int base = (by == 0) ? 0 : (by == 1) ? N_DEPT : N_DEPT + N_STORE;
    int n = (by == 0) ? N_DEPT : N_STORE;
    int i = blockIdx.x * 256 + threadIdx.x;
    if (i >= E) return;
    int d = e[E + i];
    if ((unsigned)d < (unsigned)n) atomicAdd(&counts[base + d], 1);
}

__global__ void k_scan1(const int* __restrict__ counts, int n,
                        int* __restrict__ incl, int* __restrict__ partials) {
    __shared__ int s[256];
    int t = threadIdx.x, i = blockIdx.x * 256 + t;
    int v = (i < n) ? counts[i] : 0;
    s[t] = v; __syncthreads();
    for (int o = 1; o < 256; o <<= 1) {
        int u = (t >= o) ? s[t - o] : 0;
        __syncthreads();
        s[t] += u;
        __syncthreads();
    }
    if (i < n) incl[i] = s[t];
    if (t == 255) partials[blockIdx.x] = s[255];
}

__global__ void k_scan2(int* partials, int nb) {   // 1024 threads, handles <=1024 blocks
    __shared__ int s[1024];
    int t = threadIdx.x;
    int v = (t < nb) ? partials[t] : 0;
    s[t] = v; __syncthreads();
    for (int o = 1; o < 1024; o <<= 1) {
        int u = (t >= o) ? s[t - o] : 0;
        __syncthreads();
        s[t] += u;
        __syncthreads();
    }
    if (t < nb) partials[t] = s[t];
}

__global__ void k_scan3(const int* __restrict__ counts, const int* __restrict__ incl,
                        const int* __restrict__ partials, int n, int total,
                        int* __restrict__ offs, int* __restrict__ cursor) {
    int i = blockIdx.x * 256 + threadIdx.x;
    if (i < n) {
        int base = blockIdx.x ? partials[blockIdx.x - 1] : 0;
        int e = base + incl[i] - counts[i];
        offs[i] = e;
        cursor[i] = e;
    } else if (i == n) {
        offs[n] = total;
    }
}

__global__ void k_scatter3(const int* __restrict__ e0, const int* __restrict__ e1,
                           const int* __restrict__ e2, int E,
                           int* __restrict__ cursor, int* __restrict__ srcs_all) {
    int by = blockIdx.y;
    const int* e = (by == 0) ? e0 : (by == 1) ? e1 : e2;
    int base = (by == 0) ? 0 : (by == 1) ? N_DEPT : N_DEPT + N_STORE;
    int n = (by == 0) ? N_DEPT : N_STORE;
    int i = blockIdx.x * 256 + threadIdx.x;
    if (i >= E) return;
    int d = e[E + i];
    if ((unsigned)d >= (unsigned)n) return;
    int pos = atomicAdd(&cursor[base + d], 1);
    srcs_all[pos] = e[i];
}

// ---------------- weight panel packing (MFMA B-fragment order), f32 -> bf16 ----
__global__ void k_pack_store(const float* __restrict__ Wa, const float* __restrict__ Wb,
                             const float* __restrict__ Wd1, const float* __restrict__ Wd2,
                             const float* __restrict__ aS0, const float* __restrict__ aS2,
                             const float* __restrict__ aD1, const float* __restrict__ aD2,
                             int K, u16* __restrict__ out) {
    int id = blockIdx.x * 256 + threadIdx.x;
    int total = K * 144;
    if (id >= total) return;
    int k = id / 144, n = id - k * 144;
    float val;
    if (n < 64) val = Wa[k * 64 + n];
    else if (n < 128) val = Wb[k * 64 + (n - 64)];
    else {
        int g = (n - 128) >> 2, h = (n - 128) & 3;
        const float* W = (g == 0) ? Wa : (g == 1) ? Wb : (g == 2) ? Wd1 : Wd2;
        const float* a = (g == 0) ? aS0 : (g == 1) ? aS2 : (g == 2) ? aD1 : aD2;
        float acc = 0.f;
        for (int c = 0; c < 16; ++c) acc += W[k * 64 + h * 16 + c] * a[h * 16 + c];
        val = acc;
    }
    int KT = K >> 5;
    int ct = n >> 4, col = n & 15, kt = k >> 5, q = (k >> 3) & 3, j = k & 7;
    out[(size_t)((ct * KT + kt) * 64 + q * 16 + col) * 8 + j] = f2b(val);
}

__global__ void k_pack_dept(const float* __restrict__ Ws1, const float* __restrict__ Wd0,
                            const float* __restrict__ aD0, const float* __restrict__ aS1,
                            int K, u16* __restrict__ out) {
    int id = blockIdx.x * 256 + threadIdx.x;
    int total = K * 80;
    if (id >= total) return;
    int k = id / 80, n = id - k * 80;
    float val;
    if (n < 64) val = Ws1[k * 64 + n];
    else if (n < 72) {
        int g = (n - 64) >> 2, h = (n - 64) & 3;
        const float* W = g ? Ws1 : Wd0;
        const float* a = g ? aS1 : aD0;
        float acc = 0.f;
        for (int c = 0; c < 16; ++c) acc += W[k * 64 + h * 16 + c] * a[h * 16 + c];
        val = acc;
    } else val = 0.f;
    int KT = K >> 5;
    int ct = n >> 4, col = n & 15, kt = k >> 5, q = (k >> 3) & 3, j = k & 7;
    out[(size_t)((ct * KT + kt) * 64 + q * 16 + col) * 8 + j] = f2b(val);
}

// ---------------- GEMM: wave per 16-row stripe, bf16 out; CVT=1 reads f32 A ----
template <int KT, int CVT>
__global__ void k_gemm(const void* __restrict__ Ain, int nrows, int K,
                       const u16* __restrict__ Bpanel, int CT,
                       u16* __restrict__ C, int cstride) {
    int wid = (blockIdx.x * blockDim.x + threadIdx.x) >> 6;
    int lane = threadIdx.x & 63;
    int m0 = wid << 4;
    if (m0 >= nrows) return;
    int r = lane & 15, q = lane >> 4;
    bf16x8 a[KT];
    if (CVT) {
        const float* ap = (const float*)Ain + (size_t)(m0 + r) * K + q * 8;
#pragma unroll
        for (int kt = 0; kt < KT; ++kt) {
            f32x4 f0 = *(const f32x4*)(ap + kt * 32);
            f32x4 f1 = *(const f32x4*)(ap + kt * 32 + 4);
            bf16x8 v;
#pragma unroll
            for (int j = 0; j < 4; ++j) {
                v[j]     = __builtin_bit_cast(__bf16, f2b(f0[j]));
                v[4 + j] = __builtin_bit_cast(__bf16, f2b(f1[j]));
            }
            a[kt] = v;
        }
    } else {
        const u16* ap = (const u16*)Ain + (size_t)(m0 + r) * K + q * 8;
#pragma unroll
        for (int kt = 0; kt < KT; ++kt) a[kt] = *(const bf16x8*)(ap + kt * 32);
    }
    const bf16x8* B = (const bf16x8*)Bpanel;
    for (int ct = 0; ct < CT; ++ct) {
        f32x4 acc = {0.f, 0.f, 0.f, 0.f};
#pragma unroll
        for (int kt = 0; kt < KT; ++kt)
            acc = __builtin_amdgcn_mfma_f32_16x16x32_bf16(a[kt], B[(ct * KT + kt) * 64 + lane], acc, 0, 0, 0);
        u16* cp = C + (size_t)m0 * cstride + ct * 16 + r;
#pragma unroll
        for (int i = 0; i < 4; ++i) cp[(size_t)(q * 4 + i) * cstride] = f2b(acc[i]);
    }
}

// ---------------- multi-chain CSR aggregation ----------------
// NC independent segment-chains per wave; per round of each chain:
//   phase A: lane(slot,h) computes ex for edge slot / head h (exp once per edge-head)
//   all row gathers for the round issued BEFORE ex is computed (dep only on sv)
//   phase B: ex via ds_bpermute, row via SGPR-base load; slots >= nb contribute 0.
__device__ __forceinline__ float warp16_sum(float v) {
    v += __shfl_xor(v, 1);
    v += __shfl_xor(v, 2);
    v += __shfl_xor(v, 4);
    v += __shfl_xor(v, 8);
    return v;
}

template <int NC>
__device__ __forceinline__ void run_chains(
    const int* (&srcs)[NC], const u16* (&tab)[NC],
    int (&j)[NC], int (&jend)[NC], int (&nsrc)[NC],
    int (&stride)[NC], int (&hsOff)[NC], int (&alsOff)[NC],
    float (&ald)[NC], float (&acc)[NC], float (&den)[NC],
    int lane, int slot, int h, int pbase)
{
    while (true) {
        int nb[NC]; bool anyAct = false;
#pragma unroll
        for (int i = 0; i < NC; ++i) {
            int r = jend[i] - j[i];
            nb[i] = r > 16 ? 16 : (r > 0 ? r : 0);
            anyAct |= (nb[i] > 0);
        }
        if (!anyAct) break;
        // A1: per-chain srcs batch (independent loads, issue together)
        int sv[NC];
#pragma unroll
        for (int i = 0; i < NC; ++i) {
            if (nb[i] > 0) {
                int v = srcs[i][j[i] + (slot < nb[i] ? slot : 0)];
                sv[i] = ((unsigned)v < (unsigned)nsrc[i]) ? v : 0;
            } else sv[i] = 0;
        }
        // A2: al_src gathers (dep on sv only)
        u16 avr[NC];
#pragma unroll
        for (int i = 0; i < NC; ++i)
            avr[i] = (nb[i] > 0) ? tab[i][(size_t)sv[i] * stride[i] + alsOff[i] + h] : (u16)0;
        // B-issue: ALL row gathers for the round (dep on sv only; overlap with avr)
        float hv[NC][16];
#pragma unroll
        for (int b = 0; b < 4; ++b) {
#pragma unroll
            for (int i = 0; i < NC; ++i) {
                if (nb[i] > b * 4) {
#pragma unroll
                    for (int k = b * 4; k < b * 4 + 4; ++k) {
                        int s = __builtin_amdgcn_readlane(sv[i], k);
                        hv[i][k] = b2f(tab[i][(size_t)s * stride[i] + hsOff[i] + lane]);
                    }
                }
            }
        }
        // A3: ex (waits avr; row loads stay in flight)
        int exi[NC];
#pragma unroll
        for (int i = 0; i < NC; ++i) {
            float ex = 0.f;
            if (nb[i] > 0) {
                float e = b2f(avr[i]) + ald[i];
                e = (e > 0.f) ? e : 0.2f * e;
                ex = (slot < nb[i]) ? __expf(e) : 0.f;
                den[i] += ex;
            }
            exi[i] = __builtin_bit_cast(int, ex);
        }
        // B-consume: slots >= nb have ex==0 -> contribute 0 (rows were clamped-valid)
#pragma unroll
        for (int b = 0; b < 4; ++b) {
#pragma unroll
            for (int i = 0; i < NC; ++i) {
                if (nb[i] > b * 4) {
#pragma unroll
                    for (int k = b * 4; k < b * 4 + 4; ++k) {
                        float exv = __builtin_bit_cast(float,
                            __builtin_amdgcn_ds_bpermute(pbase + (k << 2), exi[i]));
                        acc[i] = fmaf(exv, hv[i][k], acc[i]);
                    }
                }
            }
        }
#pragma unroll
        for (int i = 0; i < NC; ++i)
            if (nb[i] > 0) j[i] += 16;
    }
}

// ---------------- r0: store -> dept; 4 quarter-chains (deg ~50) ----------------
__global__ void k_agg1(const int* __restrict__ offs, const int* __restrict__ srcsA, int ndst,
                       int nsrcmax,
                       const u16* __restrict__ srcTab, int sstride, int shsOff, int salsOff,
                       const u16* __restrict__ dstTab, int dstride, int aldOff,
                       const float* __restrict__ bias, int doRelu,
                       u16* __restrict__ bOut, float* __restrict__ fOut) {
    int wid = (blockIdx.x * blockDim.x + threadIdx.x) >> 6;
    if (wid >= ndst) return;
    int lane = threadIdx.x & 63, slot = lane & 15, h = lane >> 4;
    int pbase = (lane & 48) << 2;
    float aldv = b2f(dstTab[(size_t)wid * dstride + aldOff + h]);
    int j0 = __builtin_amdgcn_readfirstlane(offs[wid]);
    int j1 = __builtin_amdgcn_readfirstlane(offs[wid + 1]);
    int cnt = j1 - j0;
    int nbat = (cnt + 15) >> 4;
    int q16 = ((nbat + 3) >> 2) << 4;   // 16-aligned quarter size
    const int* srcs[4]; const u16* tab[4];
    int j[4], jend[4], nsrc[4], stride[4], hsOff[4], alsOff[4];
    float ald[4], acc[4], den[4];
#pragma unroll
    for (int i = 0; i < 4; ++i) {
        srcs[i] = srcsA; tab[i] = srcTab;
        int s = j0 + i * q16, e = j0 + (i + 1) * q16;
        j[i] = s < j1 ? s : j1;
        jend[i] = (i == 3) ? j1 : (e < j1 ? e : j1);
        nsrc[i] = nsrcmax; stride[i] = sstride; hsOff[i] = shsOff; alsOff[i] = salsOff;
        ald[i] = aldv; acc[i] = 0.f; den[i] = 0.f;
    }
    run_chains<4>(srcs, tab, j, jend, nsrc, stride, hsOff, alsOff, ald, acc, den,
                  lane, slot, h, pbase);
    float accT = (acc[0] + acc[1]) + (acc[2] + acc[3]);
    float denT = warp16_sum((den[0] + den[1]) + (den[2] + den[3]));
    float out = accT / (denT + 1e-16f) + bias[lane];
    if (doRelu) out = out > 0.f ? out : 0.f;
    size_t oi = (size_t)wid * 64 + lane;
    if (fOut) fOut[oi] = out;
    else      bOut[oi] = f2b(out);
}

// ---------------- fused r1+r2: two relation-chains, single write ----------------
__global__ void k_agg2(const int* __restrict__ offs1, const int* __restrict__ srcsA,
                       const int* __restrict__ offs2,
                       const u16* __restrict__ projD, const u16* __restrict__ projS,
                       const float* __restrict__ bias1, const float* __restrict__ bias2,
                       int doRelu,
                       u16* __restrict__ bOut, float* __restrict__ fOut) {
    int wid = (blockIdx.x * blockDim.x + threadIdx.x) >> 6;
    if (wid >= N_STORE) return;
    int lane = threadIdx.x & 63, slot = lane & 15, h = lane >> 4;
    int pbase = (lane & 48) << 2;
    const u16* myrow = projS + (size_t)wid * 144;
    float ald1 = b2f(myrow[136 + h]);          // att_dst fold, relation 1
    float ald2 = b2f(myrow[140 + h]);          // att_dst fold, relation 2
    int a0 = __builtin_amdgcn_readfirstlane(offs1[wid]);
    int a1e = __builtin_amdgcn_readfirstlane(offs1[wid + 1]);
    int b0 = __builtin_amdgcn_readfirstlane(offs2[wid]);
    int b1e = __builtin_amdgcn_readfirstlane(offs2[wid + 1]);
    const int* srcs[2] = {srcsA, srcsA};
    const u16* tab[2]  = {projD, projS};
    int j[2]    = {a0, b0};
    int jend[2] = {a1e, b1e};
    int nsrc[2]   = {N_DEPT, N_STORE};
    int stride[2] = {80, 144};
    int hsOff[2]  = {0, 64};
    int alsOff[2] = {68, 132};
    float ald[2] = {ald1, ald2}, acc[2] = {0.f, 0.f}, den[2] = {0.f, 0.f};
    run_chains<2>(srcs, tab, j, jend, nsrc, stride, hsOff, alsOff, ald, acc, den,
                  lane, slot, h, pbase);
    float den1 = warp16_sum(den[0]);
    float den2 = warp16_sum(den[1]);
    float out = (acc[0] / (den1 + 1e-16f) + bias1[lane] +
                 acc[1] / (den2 + 1e-16f) + bias2[lane]) * 0.5f;
    if (doRelu) out = out > 0.f ? out : 0.f;
    size_t oi = (size_t)wid * 64 + lane;
    if (fOut) fOut[oi] = out;
    else      bOut[oi] = f2b(out);
}

extern "C" void kernel_launch(void* const* d_in, const int* in_sizes, int n_in,
                              void* d_out, int out_size, void* d_ws, size_t ws_size,
                              hipStream_t stream) {
    const float* x_store = (const float*)d_in[0];
    const float* x_dept  = (const float*)d_in[1];
    const int* e_sd = (const int*)d_in[2];
    const int* e_ds = (const int*)d_in[3];
    const int* e_ss = (const int*)d_in[4];
    const float* W_src0  = (const float*)d_in[5];
    const float* W_dst0  = (const float*)d_in[6];
    const float* W_src_h = (const float*)d_in[7];
    const float* W_dst_h = (const float*)d_in[8];
    const float* att_src = (const float*)d_in[9];
    const float* att_dst = (const float*)d_in[10];
    const float* bias    = (const float*)d_in[11];
    const int E = in_sizes[2] / 2;

    // ---- workspace (~64 MB) ----
    char* w = (char*)d_ws;
    auto alloc = [&](size_t bytes) -> char* {
        char* p = w;
        w += (bytes + 255) & ~(size_t)255;
        return p;
    };
    int* offs_all = (int*)alloc((size_t)(NTOT + 1) * 4);
    int* srcs_all = (int*)alloc((size_t)3 * E * 4);
    int* counts   = (int*)alloc((size_t)NTOT * 4);
    int* incl     = (int*)alloc((size_t)NTOT * 4);
    int* partials = (int*)alloc(1024 * 4);
    int* cursor   = (int*)alloc((size_t)NTOT * 4);
    u16* panelS[3]; u16* panelD[3];
    for (int l = 0; l < 3; ++l) {
        int KT = (l == 0) ? 4 : 2;
        panelS[l] = (u16*)alloc((size_t)KT * 9 * 64 * 8 * 2);
        panelD[l] = (u16*)alloc((size_t)KT * 5 * 64 * 8 * 2);
    }
    u16* projS  = (u16*)alloc((size_t)N_STORE * 144 * 2);
    u16* projD  = (u16*)alloc((size_t)N_DEPT * 80 * 2);
    u16* actSA  = (u16*)alloc((size_t)N_STORE * 64 * 2);
    u16* actDA  = (u16*)alloc((size_t)N_DEPT * 64 * 2);
    u16* actSB  = actSA;   // safe alias: gemm(l) reads A before agg(l) writes B (stream order)
    u16* actDB  = actDA;

    int* off_sd = offs_all;                      // n = N_DEPT
    int* off_ds = offs_all + N_DEPT;             // n = N_STORE
    int* off_ss = offs_all + N_DEPT + N_STORE;   // n = N_STORE

    float* outStoreF = (float*)d_out;                       // final output: f32
    float* outDeptF  = outStoreF + (size_t)N_STORE * 64;

    // ---- fused CSR build (one arena, 3 relations) ----
    int ebl = (E + 255) / 256;
    int nbN = (NTOT + 255) / 256;
    k_zeroi<<<nbN, 256, 0, stream>>>(counts, NTOT);
    k_hist3<<<dim3(ebl, 3), 256, 0, stream>>>(e_sd, e_ds, e_ss, E, counts);
    k_scan1<<<nbN, 256, 0, stream>>>(counts, NTOT, incl, partials);
    k_scan2<<<1, 1024, 0, stream>>>(partials, nbN);
    k_scan3<<<nbN + 1, 256, 0, stream>>>(counts, incl, partials, NTOT, 3 * E, offs_all, cursor);
    k_scatter3<<<dim3(ebl, 3), 256, 0, stream>>>(e_sd, e_ds, e_ss, E, cursor, srcs_all);

    // ---- layers ----
    for (int l = 0; l < 3; ++l) {
        int K = (l == 0) ? 128 : 64;
        const float *Ws[3], *Wd[3], *aS[3], *aD[3];
        for (int rr = 0; rr < 3; ++rr) {
            Ws[rr] = (l == 0) ? W_src0 + (size_t)rr * 128 * 64
                              : W_src_h + (size_t)((l - 1) * 3 + rr) * 64 * 64;
            Wd[rr] = (l == 0) ? W_dst0 + (size_t)rr * 128 * 64
                              : W_dst_h + (size_t)((l - 1) * 3 + rr) * 64 * 64;
            aS[rr] = att_src + (size_t)(l * 3 + rr) * 64;
            aD[rr] = att_dst + (size_t)(l * 3 + rr) * 64;
        }
        k_pack_store<<<(K * 144 + 255) / 256, 256, 0, stream>>>(
            Ws[0], Ws[2], Wd[1], Wd[2], aS[0], aS[2], aD[1], aD[2], K, panelS[l]);
        k_pack_dept<<<(K * 80 + 255) / 256, 256, 0, stream>>>(
            Ws[1], Wd[0], aD[0], aS[1], K, panelD[l]);

        int gbS = (N_STORE / 16 * 64 + 255) / 256;
        int gbD = (N_DEPT / 16 * 64 + 255) / 256;
        if (l == 0) {
            k_gemm<4, 1><<<gbS, 256, 0, stream>>>(x_store, N_STORE, K, panelS[l], 9, projS, 144);
            k_gemm<4, 1><<<gbD, 256, 0, stream>>>(x_dept, N_DEPT, K, panelD[l], 5, projD, 80);
        } else if (l == 1) {
            k_gemm<2, 0><<<gbS, 256, 0, stream>>>(actSA, N_STORE, K, panelS[l], 9, projS, 144);
            k_gemm<2, 0><<<gbD, 256, 0, stream>>>(actDA, N_DEPT, K, panelD[l], 5, projD, 80);
        } else {
            k_gemm<2, 0><<<gbS, 256, 0, stream>>>(actSB, N_STORE, K, panelS[l], 9, projS, 144);
            k_gemm<2, 0><<<gbD, 256, 0, stream>>>(actDB, N_DEPT, K, panelD[l], 5, projD, 80);
        }

        int relu = (l < 2) ? 1 : 0;
        u16* bS = (l == 0) ? actSA : actSB;
        u16* bD = (l == 0) ? actDA : actDB;
        float* fS = (l == 2) ? outStoreF : nullptr;
        float* fD = (l == 2) ? outDeptF  : nullptr;
        // r0: store -> dept (final write)
        k_agg1<<<N_DEPT / 4, 256, 0, stream>>>(
            off_sd, srcs_all, N_DEPT, N_STORE,
            projS, 144, 0, 128,
            projD, 80, 64,
            bias + (size_t)(l * 3 + 0) * 64, relu, bD, fD);
        // fused r1+r2 -> store output (single write)
        k_agg2<<<N_STORE / 4, 256, 0, stream>>>(
            off_ds, srcs_all, off_ss,
            projD, projS,
            bias + (size_t)(l * 3 + 1) * 64, bias + (size_t)(l * 3 + 2) * 64,
            relu, bS, fS);
    }
    (void)n_in; (void)out_size; (void)ws_size;
}

// Round 3
// 680.932 us; speedup vs baseline: 1.5647x; 1.5647x over previous
//
#include <hip/hip_runtime.h>
#include <hip/hip_bf16.h>

#define N_STORE 100000
#define N_DEPT  20000
#define F_IN    128
#define NTOT    (N_DEPT + 2 * N_STORE)   // combined CSR arena (rel0 | rel1 | rel2)

// bucketed CSR: rel0 buckets of 128 dept-nodes, rel1/2 buckets of 512 store-nodes
#define NB0   157                         // (20000+127)>>7
#define NB12  196                         // (100000+511)>>9
#define NBUCK (NB0 + 2 * NB12)            // 549

using u16    = unsigned short;
using bf16x8 = __attribute__((ext_vector_type(8))) __bf16;
using f32x4  = __attribute__((ext_vector_type(4))) float;

__device__ __forceinline__ float b2f(u16 x) {
    unsigned u = ((unsigned)x) << 16;
    return __builtin_bit_cast(float, u);
}
__device__ __forceinline__ u16 f2b(float f) {
    unsigned u = __builtin_bit_cast(unsigned, f);
    u += 0x7FFFu + ((u >> 16) & 1u);   // round-to-nearest-even
    return (u16)(u >> 16);
}

__global__ void k_zeroi(int* p, int n) {
    int i = blockIdx.x * 256 + threadIdx.x;
    if (i < n) p[i] = 0;
}

// ---------------- bucketed CSR build ----------------
// pass 1: per-block LDS histogram of buckets -> global bucket counts
__global__ void k_bcount(const int* __restrict__ e0, const int* __restrict__ e1,
                         const int* __restrict__ e2, int E, int* __restrict__ bucketCnt) {
    __shared__ int c[256];
    int t = threadIdx.x;
    c[t] = 0; __syncthreads();
    int rel = blockIdx.y;
    const int* e = (rel == 0) ? e0 : (rel == 1) ? e1 : e2;
    int n = (rel == 0) ? N_DEPT : N_STORE;
    int shift = (rel == 0) ? 7 : 9;
    int i0 = blockIdx.x * 2048 + t;
#pragma unroll
    for (int k = 0; k < 8; ++k) {
        int i = i0 + k * 256;
        if (i < E) {
            int d = e[E + i];
            if ((unsigned)d < (unsigned)n) atomicAdd(&c[d >> shift], 1);
        }
    }
    __syncthreads();
    int bbase = (rel == 0) ? 0 : (rel == 1) ? NB0 : NB0 + NB12;
    int nb = (rel == 0) ? NB0 : NB12;
    if (t < nb && c[t]) atomicAdd(&bucketCnt[bbase + t], c[t]);
}

// pass 2: scan bucket counts (549 entries) -> bucketOfs (pair regions), bucketCur
__global__ void k_bscan(const int* __restrict__ bucketCnt, int* __restrict__ bucketOfs,
                        int* __restrict__ bucketCur, int* __restrict__ offs) {
    __shared__ int s[1024];
    int t = threadIdx.x;
    int v = (t < NBUCK) ? bucketCnt[t] : 0;
    s[t] = v; __syncthreads();
    for (int o = 1; o < 1024; o <<= 1) {
        int u = (t >= o) ? s[t - o] : 0;
        __syncthreads();
        s[t] += u;
        __syncthreads();
    }
    if (t < NBUCK) {
        bucketOfs[t + 1] = s[t];
        bucketCur[t] = s[t] - v;            // exclusive
    }
    if (t == 0) bucketOfs[0] = 0;
    if (t == NBUCK - 1) offs[NTOT] = s[t];  // sentinel = total pairs
}

// pass 3: append packed (dloc<<20 | src) pairs grouped by bucket (locality-friendly)
__global__ void k_bscatter(const int* __restrict__ e0, const int* __restrict__ e1,
                           const int* __restrict__ e2, int E,
                           int* __restrict__ bucketCur, unsigned* __restrict__ pairs) {
    __shared__ int c[256];
    __shared__ int base[256];
    int t = threadIdx.x;
    c[t] = 0; __syncthreads();
    int rel = blockIdx.y;
    const int* e = (rel == 0) ? e0 : (rel == 1) ? e1 : e2;
    int n = (rel == 0) ? N_DEPT : N_STORE;
    int shift = (rel == 0) ? 7 : 9;
    int i0 = blockIdx.x * 2048 + t;
    int mb[8], mr[8]; unsigned mv[8];
#pragma unroll
    for (int k = 0; k < 8; ++k) {
        int i = i0 + k * 256;
        mb[k] = -1;
        if (i < E) {
            int d = e[E + i];
            if ((unsigned)d < (unsigned)n) {
                int b = d >> shift;
                mb[k] = b;
                mr[k] = atomicAdd(&c[b], 1);
                mv[k] = (unsigned)e[i] | ((unsigned)(d - (b << shift)) << 20);
            }
        }
    }
    __syncthreads();
    int bbase = (rel == 0) ? 0 : (rel == 1) ? NB0 : NB0 + NB12;
    int nb = (rel == 0) ? NB0 : NB12;
    if (t < nb && c[t]) base[t] = atomicAdd(&bucketCur[bbase + t], c[t]);
    __syncthreads();
#pragma unroll
    for (int k = 0; k < 8; ++k)
        if (mb[k] >= 0) pairs[base[mb[k]] + mr[k]] = mv[k];
}

// pass 4: one block per bucket -> per-node offsets + final sorted srcs (LDS atomics only)
__global__ void k_bfinal(const unsigned* __restrict__ pairs, const int* __restrict__ bucketOfs,
                         int* __restrict__ offs, int* __restrict__ srcs_all) {
    int b = blockIdx.x, t = threadIdx.x;
    int rel = (b < NB0) ? 0 : (b < NB0 + NB12) ? 1 : 2;
    int shift = (rel == 0) ? 7 : 9;
    int bLocal = b - ((rel == 0) ? 0 : (rel == 1) ? NB0 : NB0 + NB12);
    int n = (rel == 0) ? N_DEPT : N_STORE;
    int gbase = (rel == 0) ? 0 : (rel == 1) ? N_DEPT : N_DEPT + N_STORE;
    int nodeLo = bLocal << shift;
    int bsize = 1 << shift;
    int nNodes = n - nodeLo; if (nNodes > bsize) nNodes = bsize;
    int pairLo = bucketOfs[b], pairHi = bucketOfs[b + 1];
    __shared__ int cnt[512], sc[512];
    cnt[t] = 0; cnt[t + 256] = 0;
    __syncthreads();
    for (int p = pairLo + t; p < pairHi; p += 256)
        atomicAdd(&cnt[pairs[p] >> 20], 1);
    __syncthreads();
    sc[t] = cnt[t]; sc[t + 256] = cnt[t + 256];
    __syncthreads();
    for (int o = 1; o < 512; o <<= 1) {
        int a0 = (t >= o) ? sc[t - o] : 0;
        int a1 = (t + 256 >= o) ? sc[t + 256 - o] : 0;
        __syncthreads();
        sc[t] += a0; sc[t + 256] += a1;
        __syncthreads();
    }
    int ex0 = sc[t] - cnt[t];
    int ex1 = sc[t + 256] - cnt[t + 256];
    if (t < nNodes)       offs[gbase + nodeLo + t]       = pairLo + ex0;
    if (t + 256 < nNodes) offs[gbase + nodeLo + t + 256] = pairLo + ex1;
    __syncthreads();
    cnt[t] = ex0; cnt[t + 256] = ex1;     // reuse as cursors
    __syncthreads();
    for (int p = pairLo + t; p < pairHi; p += 256) {
        unsigned u = pairs[p];
        int q = atomicAdd(&cnt[u >> 20], 1);
        srcs_all[pairLo + q] = (int)(u & 0xFFFFFu);
    }
}

// ---------------- weight panel packing (MFMA B-fragment order), f32 -> bf16 ----
__global__ void k_pack_store(const float* __restrict__ Wa, const float* __restrict__ Wb,
                             const float* __restrict__ Wd1, const float* __restrict__ Wd2,
                             const float* __restrict__ aS0, const float* __restrict__ aS2,
                             const float* __restrict__ aD1, const float* __restrict__ aD2,
                             int K, u16* __restrict__ out) {
    int id = blockIdx.x * 256 + threadIdx.x;
    int total = K * 144;
    if (id >= total) return;
    int k = id / 144, n = id - k * 144;
    float val;
    if (n < 64) val = Wa[k * 64 + n];
    else if (n < 128) val = Wb[k * 64 + (n - 64)];
    else {
        int g = (n - 128) >> 2, h = (n - 128) & 3;
        const float* W = (g == 0) ? Wa : (g == 1) ? Wb : (g == 2) ? Wd1 : Wd2;
        const float* a = (g == 0) ? aS0 : (g == 1) ? aS2 : (g == 2) ? aD1 : aD2;
        float acc = 0.f;
        for (int c = 0; c < 16; ++c) acc += W[k * 64 + h * 16 + c] * a[h * 16 + c];
        val = acc;
    }
    int KT = K >> 5;
    int ct = n >> 4, col = n & 15, kt = k >> 5, q = (k >> 3) & 3, j = k & 7;
    out[(size_t)((ct * KT + kt) * 64 + q * 16 + col) * 8 + j] = f2b(val);
}

__global__ void k_pack_dept(const float* __restrict__ Ws1, const float* __restrict__ Wd0,
                            const float* __restrict__ aD0, const float* __restrict__ aS1,
                            int K, u16* __restrict__ out) {
    int id = blockIdx.x * 256 + threadIdx.x;
    int total = K * 80;
    if (id >= total) return;
    int k = id / 80, n = id - k * 80;
    float val;
    if (n < 64) val = Ws1[k * 64 + n];
    else if (n < 72) {
        int g = (n - 64) >> 2, h = (n - 64) & 3;
        const float* W = g ? Ws1 : Wd0;
        const float* a = g ? aS1 : aD0;
        float acc = 0.f;
        for (int c = 0; c < 16; ++c) acc += W[k * 64 + h * 16 + c] * a[h * 16 + c];
        val = acc;
    } else val = 0.f;
    int KT = K >> 5;
    int ct = n >> 4, col = n & 15, kt = k >> 5, q = (k >> 3) & 3, j = k & 7;
    out[(size_t)((ct * KT + kt) * 64 + q * 16 + col) * 8 + j] = f2b(val);
}

// ---------------- GEMM: wave per 16-row stripe, bf16 out; CVT=1 reads f32 A ----
template <int KT, int CVT>
__global__ void k_gemm(const void* __restrict__ Ain, int nrows, int K,
                       const u16* __restrict__ Bpanel, int CT,
                       u16* __restrict__ C, int cstride) {
    int wid = (blockIdx.x * blockDim.x + threadIdx.x) >> 6;
    int lane = threadIdx.x & 63;
    int m0 = wid << 4;
    if (m0 >= nrows) return;
    int r = lane & 15, q = lane >> 4;
    bf16x8 a[KT];
    if (CVT) {
        const float* ap = (const float*)Ain + (size_t)(m0 + r) * K + q * 8;
#pragma unroll
        for (int kt = 0; kt < KT; ++kt) {
            f32x4 f0 = *(const f32x4*)(ap + kt * 32);
            f32x4 f1 = *(const f32x4*)(ap + kt * 32 + 4);
            bf16x8 v;
#pragma unroll
            for (int j = 0; j < 4; ++j) {
                v[j]     = __builtin_bit_cast(__bf16, f2b(f0[j]));
                v[4 + j] = __builtin_bit_cast(__bf16, f2b(f1[j]));
            }
            a[kt] = v;
        }
    } else {
        const u16* ap = (const u16*)Ain + (size_t)(m0 + r) * K + q * 8;
#pragma unroll
        for (int kt = 0; kt < KT; ++kt) a[kt] = *(const bf16x8*)(ap + kt * 32);
    }
    const bf16x8* B = (const bf16x8*)Bpanel;
    for (int ct = 0; ct < CT; ++ct) {
        f32x4 acc = {0.f, 0.f, 0.f, 0.f};
#pragma unroll
        for (int kt = 0; kt < KT; ++kt)
            acc = __builtin_amdgcn_mfma_f32_16x16x32_bf16(a[kt], B[(ct * KT + kt) * 64 + lane], acc, 0, 0, 0);
        u16* cp = C + (size_t)m0 * cstride + ct * 16 + r;
#pragma unroll
        for (int i = 0; i < 4; ++i) cp[(size_t)(q * 4 + i) * cstride] = f2b(acc[i]);
    }
}

// ---------------- aggregation (round-1 proven): 16-edge batches, dedup'd softmax ----
__device__ __forceinline__ float warp16_sum(float v) {
    v += __shfl_xor(v, 1);
    v += __shfl_xor(v, 2);
    v += __shfl_xor(v, 4);
    v += __shfl_xor(v, 8);
    return v;
}

template <int UB>
__device__ __forceinline__ void agg_seg(const int* __restrict__ srcs, int j0, int j1, int nsrc,
                                        const u16* __restrict__ tab, int stride, int hsOff, int alsOff,
                                        int lane, int slot, int h, int pbase, float ald,
                                        float& acc, float& den) {
    for (int j = j0; j < j1; j += 16) {
        int nb = j1 - j; if (nb > 16) nb = 16;
        // --- phase A: per-(edge,head) attention logit ---
        int sv = srcs[j + (slot < nb ? slot : 0)];
        sv = ((unsigned)sv < (unsigned)nsrc) ? sv : 0;
        float av = b2f(tab[(size_t)sv * stride + alsOff + h]);
        float e = av + ald;
        e = (e > 0.f) ? e : 0.2f * e;
        float ex = (slot < nb) ? __expf(e) : 0.f;
        den += ex;
        int exi = __builtin_bit_cast(int, ex);
        // --- phase B: weighted row accumulate ---
        for (int jj = 0; jj < nb; ) {
            int m = nb - jj; if (m > UB) m = UB;
            float exk[UB], hvk[UB];
#pragma unroll
            for (int k = 0; k < UB; ++k) {
                int idx = jj + (k < m ? k : 0);
                int s = __builtin_amdgcn_readlane(sv, idx);          // SGPR row index
                exk[k] = __builtin_bit_cast(float,
                         __builtin_amdgcn_ds_bpermute(pbase + (idx << 2), exi));
                hvk[k] = b2f(tab[(size_t)s * stride + hsOff + lane]); // SGPR base + lane off
            }
#pragma unroll
            for (int k = 0; k < UB; ++k)
                if (k < m) acc = fmaf(exk[k], hvk[k], acc);
            jj += m;
        }
    }
}

// ---------------- r0: store -> dept, single relation, final write ----------------
__global__ void k_agg1(const int* __restrict__ offs, const int* __restrict__ srcs, int ndst,
                       int nsrcmax,
                       const u16* __restrict__ srcTab, int sstride, int hsOff, int alsOff,
                       const u16* __restrict__ dstTab, int dstride, int aldOff,
                       const float* __restrict__ bias, int doRelu,
                       u16* __restrict__ bOut, float* __restrict__ fOut) {
    int wid = (blockIdx.x * blockDim.x + threadIdx.x) >> 6;
    if (wid >= ndst) return;
    int lane = threadIdx.x & 63, slot = lane & 15, h = lane >> 4;
    int pbase = (lane & 48) << 2;
    float ald = b2f(dstTab[(size_t)wid * dstride + aldOff + h]);
    int j0 = __builtin_amdgcn_readfirstlane(offs[wid]);
    int j1 = __builtin_amdgcn_readfirstlane(offs[wid + 1]);
    float acc = 0.f, den = 0.f;
    agg_seg<8>(srcs, j0, j1, nsrcmax, srcTab, sstride, hsOff, alsOff,
               lane, slot, h, pbase, ald, acc, den);
    den = warp16_sum(den);
    float out = acc / (den + 1e-16f) + bias[lane];
    if (doRelu) out = out > 0.f ? out : 0.f;
    size_t oi = (size_t)wid * 64 + lane;
    if (fOut) fOut[oi] = out;
    else      bOut[oi] = f2b(out);
}

// ---------------- fused r1+r2: dept->store + store->store, single write ----------------
__global__ void k_agg2(const int* __restrict__ offs1, const int* __restrict__ srcs,
                       const int* __restrict__ offs2,
                       const u16* __restrict__ projD, const u16* __restrict__ projS,
                       const float* __restrict__ bias1, const float* __restrict__ bias2,
                       int doRelu,
                       u16* __restrict__ bOut, float* __restrict__ fOut) {
    int wid = (blockIdx.x * blockDim.x + threadIdx.x) >> 6;
    if (wid >= N_STORE) return;
    int lane = threadIdx.x & 63, slot = lane & 15, h = lane >> 4;
    int pbase = (lane & 48) << 2;
    const u16* myrow = projS + (size_t)wid * 144;
    float ald1 = b2f(myrow[136 + h]);          // att_dst fold, relation 1
    float ald2 = b2f(myrow[140 + h]);          // att_dst fold, relation 2
    int a0 = __builtin_amdgcn_readfirstlane(offs1[wid]);
    int a1e = __builtin_amdgcn_readfirstlane(offs1[wid + 1]);
    int b0 = __builtin_amdgcn_readfirstlane(offs2[wid]);
    int b1e = __builtin_amdgcn_readfirstlane(offs2[wid + 1]);
    float acc1 = 0.f, den1 = 0.f, acc2 = 0.f, den2 = 0.f;
    // r1: gather dept rows (stride 80, hs 0, als 68)
    agg_seg<8>(srcs, a0, a1e, N_DEPT, projD, 80, 0, 68,
               lane, slot, h, pbase, ald1, acc1, den1);
    // r2: gather store rows (stride 144, hs 64, als 132)
    agg_seg<8>(srcs, b0, b1e, N_STORE, projS, 144, 64, 132,
               lane, slot, h, pbase, ald2, acc2, den2);
    den1 = warp16_sum(den1);
    den2 = warp16_sum(den2);
    float out = (acc1 / (den1 + 1e-16f) + bias1[lane] + acc2 / (den2 + 1e-16f) + bias2[lane]) * 0.5f;
    if (doRelu) out = out > 0.f ? out : 0.f;
    size_t oi = (size_t)wid * 64 + lane;
    if (fOut) fOut[oi] = out;
    else      bOut[oi] = f2b(out);
}

extern "C" void kernel_launch(void* const* d_in, const int* in_sizes, int n_in,
                              void* d_out, int out_size, void* d_ws, size_t ws_size,
                              hipStream_t stream) {
    const float* x_store = (const float*)d_in[0];
    const float* x_dept  = (const float*)d_in[1];
    const int* e_sd = (const int*)d_in[2];
    const int* e_ds = (const int*)d_in[3];
    const int* e_ss = (const int*)d_in[4];
    const float* W_src0  = (const float*)d_in[5];
    const float* W_dst0  = (const float*)d_in[6];
    const float* W_src_h = (const float*)d_in[7];
    const float* W_dst_h = (const float*)d_in[8];
    const float* att_src = (const float*)d_in[9];
    const float* att_dst = (const float*)d_in[10];
    const float* bias    = (const float*)d_in[11];
    const int E = in_sizes[2] / 2;

    // ---- workspace (~61 MB) ----
    char* w = (char*)d_ws;
    auto alloc = [&](size_t bytes) -> char* {
        char* p = w;
        w += (bytes + 255) & ~(size_t)255;
        return p;
    };
    int* offs_all  = (int*)alloc((size_t)(NTOT + 1) * 4);
    int* srcs_all  = (int*)alloc((size_t)3 * E * 4);
    int* bucketCnt = (int*)alloc(1024 * 4);
    int* bucketOfs = (int*)alloc(1024 * 4);
    int* bucketCur = (int*)alloc(1024 * 4);
    u16* panelS[3]; u16* panelD[3];
    for (int l = 0; l < 3; ++l) {
        int KT = (l == 0) ? 4 : 2;
        panelS[l] = (u16*)alloc((size_t)KT * 9 * 64 * 8 * 2);
        panelD[l] = (u16*)alloc((size_t)KT * 5 * 64 * 8 * 2);
    }
    u16* projS  = (u16*)alloc((size_t)N_STORE * 144 * 2);
    u16* projD  = (u16*)alloc((size_t)N_DEPT * 80 * 2);
    u16* actSA  = (u16*)alloc((size_t)N_STORE * 64 * 2);
    u16* actDA  = (u16*)alloc((size_t)N_DEPT * 64 * 2);
    u16* actSB  = actSA;                     // safe alias (stream-ordered)
    u16* actDB  = actDA;
    unsigned* pairs = (unsigned*)projS;      // 12 MB staging, dead before projS is written

    int* off_sd = offs_all;                      // n = N_DEPT
    int* off_ds = offs_all + N_DEPT;             // n = N_STORE
    int* off_ss = offs_all + N_DEPT + N_STORE;   // n = N_STORE

    float* outStoreF = (float*)d_out;                       // final output: f32
    float* outDeptF  = outStoreF + (size_t)N_STORE * 64;

    // ---- bucketed CSR build ----
    int ebl8 = (E + 2047) / 2048;
    k_zeroi<<<(NBUCK + 255) / 256, 256, 0, stream>>>(bucketCnt, NBUCK);
    k_bcount<<<dim3(ebl8, 3), 256, 0, stream>>>(e_sd, e_ds, e_ss, E, bucketCnt);
    k_bscan<<<1, 1024, 0, stream>>>(bucketCnt, bucketOfs, bucketCur, offs_all);
    k_bscatter<<<dim3(ebl8, 3), 256, 0, stream>>>(e_sd, e_ds, e_ss, E, bucketCur, pairs);
    k_bfinal<<<NBUCK, 256, 0, stream>>>(pairs, bucketOfs, offs_all, srcs_all);

    // ---- layers ----
    for (int l = 0; l < 3; ++l) {
        int K = (l == 0) ? 128 : 64;
        const float *Ws[3], *Wd[3], *aS[3], *aD[3];
        for (int rr = 0; rr < 3; ++rr) {
            Ws[rr] = (l == 0) ? W_src0 + (size_t)rr * 128 * 64
                              : W_src_h + (size_t)((l - 1) * 3 + rr) * 64 * 64;
            Wd[rr] = (l == 0) ? W_dst0 + (size_t)rr * 128 * 64
                              : W_dst_h + (size_t)((l - 1) * 3 + rr) * 64 * 64;
            aS[rr] = att_src + (size_t)(l * 3 + rr) * 64;
            aD[rr] = att_dst + (size_t)(l * 3 + rr) * 64;
        }
        k_pack_store<<<(K * 144 + 255) / 256, 256, 0, stream>>>(
            Ws[0], Ws[2], Wd[1], Wd[2], aS[0], aS[2], aD[1], aD[2], K, panelS[l]);
        k_pack_dept<<<(K * 80 + 255) / 256, 256, 0, stream>>>(
            Ws[1], Wd[0], aD[0], aS[1], K, panelD[l]);

        int gbS = (N_STORE / 16 * 64 + 255) / 256;
        int gbD = (N_DEPT / 16 * 64 + 255) / 256;
        if (l == 0) {
            k_gemm<4, 1><<<gbS, 256, 0, stream>>>(x_store, N_STORE, K, panelS[l], 9, projS, 144);
            k_gemm<4, 1><<<gbD, 256, 0, stream>>>(x_dept, N_DEPT, K, panelD[l], 5, projD, 80);
        } else if (l == 1) {
            k_gemm<2, 0><<<gbS, 256, 0, stream>>>(actSA, N_STORE, K, panelS[l], 9, projS, 144);
            k_gemm<2, 0><<<gbD, 256, 0, stream>>>(actDA, N_DEPT, K, panelD[l], 5, projD, 80);
        } else {
            k_gemm<2, 0><<<gbS, 256, 0, stream>>>(actSB, N_STORE, K, panelS[l], 9, projS, 144);
            k_gemm<2, 0><<<gbD, 256, 0, stream>>>(actDB, N_DEPT, K, panelD[l], 5, projD, 80);
        }

        int relu = (l < 2) ? 1 : 0;
        u16* bS = (l == 0) ? actSA : actSB;
        u16* bD = (l == 0) ? actDA : actDB;
        float* fS = (l == 2) ? outStoreF : nullptr;
        float* fD = (l == 2) ? outDeptF  : nullptr;
        // r0: store -> dept (final write)
        k_agg1<<<N_DEPT / 4, 256, 0, stream>>>(
            off_sd, srcs_all, N_DEPT, N_STORE,
            projS, 144, 0, 128,
            projD, 80, 64,
            bias + (size_t)(l * 3 + 0) * 64, relu, bD, fD);
        // fused r1+r2 -> store output (single write)
        k_agg2<<<N_STORE / 4, 256, 0, stream>>>(
            off_ds, srcs_all, off_ss,
            projD, projS,
            bias + (size_t)(l * 3 + 1) * 64, bias + (size_t)(l * 3 + 2) * 64,
            relu, bS, fS);
    }
    (void)n_in; (void)out_size; (void)ws_size;
}

// Round 4
// 578.481 us; speedup vs baseline: 1.8419x; 1.1771x over previous
//
#include <hip/hip_runtime.h>
#include <hip/hip_bf16.h>

#define N_STORE 100000
#define N_DEPT  20000
#define F_IN    128
#define NTOT    (N_DEPT + 2 * N_STORE)   // combined CSR arena (rel0 | rel1 | rel2)

// bucketed CSR: rel0 buckets of 128 dept-nodes, rel1/2 buckets of 512 store-nodes
#define NB0   157                         // (20000+127)>>7
#define NB12  196                         // (100000+511)>>9
#define NBUCK (NB0 + 2 * NB12)            // 549

using u16    = unsigned short;
using bf16x8 = __attribute__((ext_vector_type(8))) __bf16;
using f32x4  = __attribute__((ext_vector_type(4))) float;

__device__ __forceinline__ float b2f(u16 x) {
    unsigned u = ((unsigned)x) << 16;
    return __builtin_bit_cast(float, u);
}
__device__ __forceinline__ u16 f2b(float f) {
    unsigned u = __builtin_bit_cast(unsigned, f);
    u += 0x7FFFu + ((u >> 16) & 1u);   // round-to-nearest-even
    return (u16)(u >> 16);
}

__global__ void k_zeroi(int* p, int n) {
    int i = blockIdx.x * 256 + threadIdx.x;
    if (i < n) p[i] = 0;
}

// ---------------- bucketed CSR build ----------------
__global__ void k_bcount(const int* __restrict__ e0, const int* __restrict__ e1,
                         const int* __restrict__ e2, int E, int* __restrict__ bucketCnt) {
    __shared__ int c[256];
    int t = threadIdx.x;
    c[t] = 0; __syncthreads();
    int rel = blockIdx.y;
    const int* e = (rel == 0) ? e0 : (rel == 1) ? e1 : e2;
    int n = (rel == 0) ? N_DEPT : N_STORE;
    int shift = (rel == 0) ? 7 : 9;
    int i0 = blockIdx.x * 2048 + t;
#pragma unroll
    for (int k = 0; k < 8; ++k) {
        int i = i0 + k * 256;
        if (i < E) {
            int d = e[E + i];
            if ((unsigned)d < (unsigned)n) atomicAdd(&c[d >> shift], 1);
        }
    }
    __syncthreads();
    int bbase = (rel == 0) ? 0 : (rel == 1) ? NB0 : NB0 + NB12;
    int nb = (rel == 0) ? NB0 : NB12;
    if (t < nb && c[t]) atomicAdd(&bucketCnt[bbase + t], c[t]);
}

__global__ void k_bscan(const int* __restrict__ bucketCnt, int* __restrict__ bucketOfs,
                        int* __restrict__ bucketCur, int* __restrict__ offs) {
    __shared__ int s[1024];
    int t = threadIdx.x;
    int v = (t < NBUCK) ? bucketCnt[t] : 0;
    s[t] = v; __syncthreads();
    for (int o = 1; o < 1024; o <<= 1) {
        int u = (t >= o) ? s[t - o] : 0;
        __syncthreads();
        s[t] += u;
        __syncthreads();
    }
    if (t < NBUCK) {
        bucketOfs[t + 1] = s[t];
        bucketCur[t] = s[t] - v;            // exclusive
    }
    if (t == 0) bucketOfs[0] = 0;
    if (t == NBUCK - 1) offs[NTOT] = s[t];  // sentinel = total pairs
}

__global__ void k_bscatter(const int* __restrict__ e0, const int* __restrict__ e1,
                           const int* __restrict__ e2, int E,
                           int* __restrict__ bucketCur, unsigned* __restrict__ pairs) {
    __shared__ int c[256];
    __shared__ int base[256];
    int t = threadIdx.x;
    c[t] = 0; __syncthreads();
    int rel = blockIdx.y;
    const int* e = (rel == 0) ? e0 : (rel == 1) ? e1 : e2;
    int n = (rel == 0) ? N_DEPT : N_STORE;
    int shift = (rel == 0) ? 7 : 9;
    int i0 = blockIdx.x * 2048 + t;
    int mb[8], mr[8]; unsigned mv[8];
#pragma unroll
    for (int k = 0; k < 8; ++k) {
        int i = i0 + k * 256;
        mb[k] = -1;
        if (i < E) {
            int d = e[E + i];
            if ((unsigned)d < (unsigned)n) {
                int b = d >> shift;
                mb[k] = b;
                mr[k] = atomicAdd(&c[b], 1);
                mv[k] = (unsigned)e[i] | ((unsigned)(d - (b << shift)) << 20);
            }
        }
    }
    __syncthreads();
    int bbase = (rel == 0) ? 0 : (rel == 1) ? NB0 : NB0 + NB12;
    int nb = (rel == 0) ? NB0 : NB12;
    if (t < nb && c[t]) base[t] = atomicAdd(&bucketCur[bbase + t], c[t]);
    __syncthreads();
#pragma unroll
    for (int k = 0; k < 8; ++k)
        if (mb[k] >= 0) pairs[base[mb[k]] + mr[k]] = mv[k];
}

__global__ void k_bfinal(const unsigned* __restrict__ pairs, const int* __restrict__ bucketOfs,
                         int* __restrict__ offs, int* __restrict__ srcs_all) {
    int b = blockIdx.x, t = threadIdx.x;
    int rel = (b < NB0) ? 0 : (b < NB0 + NB12) ? 1 : 2;
    int shift = (rel == 0) ? 7 : 9;
    int bLocal = b - ((rel == 0) ? 0 : (rel == 1) ? NB0 : NB0 + NB12);
    int n = (rel == 0) ? N_DEPT : N_STORE;
    int gbase = (rel == 0) ? 0 : (rel == 1) ? N_DEPT : N_DEPT + N_STORE;
    int nodeLo = bLocal << shift;
    int bsize = 1 << shift;
    int nNodes = n - nodeLo; if (nNodes > bsize) nNodes = bsize;
    int pairLo = bucketOfs[b], pairHi = bucketOfs[b + 1];
    __shared__ int cnt[512], sc[512];
    cnt[t] = 0; cnt[t + 256] = 0;
    __syncthreads();
    for (int p = pairLo + t; p < pairHi; p += 256)
        atomicAdd(&cnt[pairs[p] >> 20], 1);
    __syncthreads();
    sc[t] = cnt[t]; sc[t + 256] = cnt[t + 256];
    __syncthreads();
    for (int o = 1; o < 512; o <<= 1) {
        int a0 = (t >= o) ? sc[t - o] : 0;
        int a1 = (t + 256 >= o) ? sc[t + 256 - o] : 0;
        __syncthreads();
        sc[t] += a0; sc[t + 256] += a1;
        __syncthreads();
    }
    int ex0 = sc[t] - cnt[t];
    int ex1 = sc[t + 256] - cnt[t + 256];
    if (t < nNodes)       offs[gbase + nodeLo + t]       = pairLo + ex0;
    if (t + 256 < nNodes) offs[gbase + nodeLo + t + 256] = pairLo + ex1;
    __syncthreads();
    cnt[t] = ex0; cnt[t + 256] = ex1;     // reuse as cursors
    __syncthreads();
    for (int p = pairLo + t; p < pairHi; p += 256) {
        unsigned u = pairs[p];
        int q = atomicAdd(&cnt[u >> 20], 1);
        srcs_all[pairLo + q] = (int)(u & 0xFFFFFu);
    }
}

// ---------------- weight panel packing (MFMA B-fragment order), f32 -> bf16 ----
__global__ void k_pack_store(const float* __restrict__ Wa, const float* __restrict__ Wb,
                             const float* __restrict__ Wd1, const float* __restrict__ Wd2,
                             const float* __restrict__ aS0, const float* __restrict__ aS2,
                             const float* __restrict__ aD1, const float* __restrict__ aD2,
                             int K, u16* __restrict__ out) {
    int id = blockIdx.x * 256 + threadIdx.x;
    int total = K * 144;
    if (id >= total) return;
    int k = id / 144, n = id - k * 144;
    float val;
    if (n < 64) val = Wa[k * 64 + n];
    else if (n < 128) val = Wb[k * 64 + (n - 64)];
    else {
        int g = (n - 128) >> 2, h = (n - 128) & 3;
        const float* W = (g == 0) ? Wa : (g == 1) ? Wb : (g == 2) ? Wd1 : Wd2;
        const float* a = (g == 0) ? aS0 : (g == 1) ? aS2 : (g == 2) ? aD1 : aD2;
        float acc = 0.f;
        for (int c = 0; c < 16; ++c) acc += W[k * 64 + h * 16 + c] * a[h * 16 + c];
        val = acc;
    }
    int KT = K >> 5;
    int ct = n >> 4, col = n & 15, kt = k >> 5, q = (k >> 3) & 3, j = k & 7;
    out[(size_t)((ct * KT + kt) * 64 + q * 16 + col) * 8 + j] = f2b(val);
}

__global__ void k_pack_dept(const float* __restrict__ Ws1, const float* __restrict__ Wd0,
                            const float* __restrict__ aD0, const float* __restrict__ aS1,
                            int K, u16* __restrict__ out) {
    int id = blockIdx.x * 256 + threadIdx.x;
    int total = K * 80;
    if (id >= total) return;
    int k = id / 80, n = id - k * 80;
    float val;
    if (n < 64) val = Ws1[k * 64 + n];
    else if (n < 72) {
        int g = (n - 64) >> 2, h = (n - 64) & 3;
        const float* W = g ? Ws1 : Wd0;
        const float* a = g ? aS1 : aD0;
        float acc = 0.f;
        for (int c = 0; c < 16; ++c) acc += W[k * 64 + h * 16 + c] * a[h * 16 + c];
        val = acc;
    } else val = 0.f;
    int KT = K >> 5;
    int ct = n >> 4, col = n & 15, kt = k >> 5, q = (k >> 3) & 3, j = k & 7;
    out[(size_t)((ct * KT + kt) * 64 + q * 16 + col) * 8 + j] = f2b(val);
}

// ---------------- GEMM: wave per 16-row stripe; split-table epilogue ----------------
// MODE 0 (store): CT=9 -> H0 (cols 0-63), H1 (cols 64-127), AL (16 scalar cols)
// MODE 1 (dept):  CT=5 -> H0 (cols 0-63), AL (16 scalar cols)
template <int KT, int CVT, int MODE>
__global__ void k_gemm(const void* __restrict__ Ain, int nrows, int K,
                       const u16* __restrict__ Bpanel,
                       u16* __restrict__ H0, u16* __restrict__ H1, u16* __restrict__ AL) {
    const int CT = (MODE == 0) ? 9 : 5;
    int wid = (blockIdx.x * blockDim.x + threadIdx.x) >> 6;
    int lane = threadIdx.x & 63;
    int m0 = wid << 4;
    if (m0 >= nrows) return;
    int r = lane & 15, q = lane >> 4;
    bf16x8 a[KT];
    if (CVT) {
        const float* ap = (const float*)Ain + (size_t)(m0 + r) * K + q * 8;
#pragma unroll
        for (int kt = 0; kt < KT; ++kt) {
            f32x4 f0 = *(const f32x4*)(ap + kt * 32);
            f32x4 f1 = *(const f32x4*)(ap + kt * 32 + 4);
            bf16x8 v;
#pragma unroll
            for (int j = 0; j < 4; ++j) {
                v[j]     = __builtin_bit_cast(__bf16, f2b(f0[j]));
                v[4 + j] = __builtin_bit_cast(__bf16, f2b(f1[j]));
            }
            a[kt] = v;
        }
    } else {
        const u16* ap = (const u16*)Ain + (size_t)(m0 + r) * K + q * 8;
#pragma unroll
        for (int kt = 0; kt < KT; ++kt) a[kt] = *(const bf16x8*)(ap + kt * 32);
    }
    const bf16x8* B = (const bf16x8*)Bpanel;
    int rowb = m0 + q * 4;
#pragma unroll
    for (int ct = 0; ct < CT; ++ct) {
        f32x4 acc = {0.f, 0.f, 0.f, 0.f};
#pragma unroll
        for (int kt = 0; kt < KT; ++kt)
            acc = __builtin_amdgcn_mfma_f32_16x16x32_bf16(a[kt], B[(ct * KT + kt) * 64 + lane], acc, 0, 0, 0);
        if (MODE == 0) {
            if (ct < 4) {
                u16* cp = H0 + (size_t)rowb * 64 + ct * 16 + r;
#pragma unroll
                for (int i = 0; i < 4; ++i) cp[(size_t)i * 64] = f2b(acc[i]);
            } else if (ct < 8) {
                u16* cp = H1 + (size_t)rowb * 64 + (ct - 4) * 16 + r;
#pragma unroll
                for (int i = 0; i < 4; ++i) cp[(size_t)i * 64] = f2b(acc[i]);
            } else {
                u16* cp = AL + (size_t)rowb * 16 + r;
#pragma unroll
                for (int i = 0; i < 4; ++i) cp[(size_t)i * 16] = f2b(acc[i]);
            }
        } else {
            if (ct < 4) {
                u16* cp = H0 + (size_t)rowb * 64 + ct * 16 + r;
#pragma unroll
                for (int i = 0; i < 4; ++i) cp[(size_t)i * 64] = f2b(acc[i]);
            } else {
                u16* cp = AL + (size_t)rowb * 16 + r;
#pragma unroll
                for (int i = 0; i < 4; ++i) cp[(size_t)i * 16] = f2b(acc[i]);
            }
        }
    }
}

// ---------------- aggregation: aligned 128B h-gathers + L2-resident al tables ----
// per 16-edge round: al gather issued first, then ALL 16 row gathers (dep on sv only),
// then exp (overlaps in-flight gathers), then bpermute+fma drain.
__device__ __forceinline__ float warp16_sum(float v) {
    v += __shfl_xor(v, 1);
    v += __shfl_xor(v, 2);
    v += __shfl_xor(v, 4);
    v += __shfl_xor(v, 8);
    return v;
}

__device__ __forceinline__ void agg_seg(const int* __restrict__ srcs, int j0, int j1, int nsrc,
                                        const u16* __restrict__ htab, const u16* __restrict__ altab,
                                        int alsOff, int lane, int slot, int h, int pbase, float ald,
                                        float& acc, float& den) {
    for (int j = j0; j < j1; j += 16) {
        int nb = j1 - j; if (nb > 16) nb = 16;
        int sv = srcs[j + (slot < nb ? slot : 0)];
        sv = ((unsigned)sv < (unsigned)nsrc) ? sv : 0;
        // al gather first (longest dep chain: load -> exp -> bpermute)
        u16 avr = altab[(size_t)sv * 16 + alsOff + h];
        // all 16 row gathers (SGPR base via readlane, aligned 128B rows)
        float hv[16];
#pragma unroll
        for (int k = 0; k < 16; ++k) {
            int s = __builtin_amdgcn_readlane(sv, k);
            hv[k] = b2f(htab[(size_t)s * 64 + lane]);
        }
        float e = b2f(avr) + ald;
        e = (e > 0.f) ? e : 0.2f * e;
        float ex = (slot < nb) ? __expf(e) : 0.f;
        den += ex;
        int exi = __builtin_bit_cast(int, ex);
#pragma unroll
        for (int k = 0; k < 16; ++k) {
            float exv = __builtin_bit_cast(float,
                __builtin_amdgcn_ds_bpermute(pbase + (k << 2), exi));
            acc = fmaf(exv, hv[k], acc);
        }
    }
}

// ---------------- r0: store -> dept, single relation, final write ----------------
__global__ void k_agg1(const int* __restrict__ offs, const int* __restrict__ srcs,
                       const u16* __restrict__ hS0, const u16* __restrict__ alS,
                       const u16* __restrict__ alD,
                       const float* __restrict__ bias, int doRelu,
                       u16* __restrict__ bOut, float* __restrict__ fOut) {
    int wid = (blockIdx.x * blockDim.x + threadIdx.x) >> 6;
    if (wid >= N_DEPT) return;
    int lane = threadIdx.x & 63, slot = lane & 15, h = lane >> 4;
    int pbase = (lane & 48) << 2;
    float ald = b2f(alD[(size_t)wid * 16 + 0 + h]);       // ald_r0
    int j0 = __builtin_amdgcn_readfirstlane(offs[wid]);
    int j1 = __builtin_amdgcn_readfirstlane(offs[wid + 1]);
    float acc = 0.f, den = 0.f;
    agg_seg(srcs, j0, j1, N_STORE, hS0, alS, 0, lane, slot, h, pbase, ald, acc, den);
    den = warp16_sum(den);
    float out = acc / (den + 1e-16f) + bias[lane];
    if (doRelu) out = out > 0.f ? out : 0.f;
    size_t oi = (size_t)wid * 64 + lane;
    if (fOut) fOut[oi] = out;
    else      bOut[oi] = f2b(out);
}

// ---------------- fused r1+r2: dept->store + store->store, single write ----------------
__global__ void k_agg2(const int* __restrict__ offs1, const int* __restrict__ srcs,
                       const int* __restrict__ offs2,
                       const u16* __restrict__ hD, const u16* __restrict__ alD,
                       const u16* __restrict__ hS2, const u16* __restrict__ alS,
                       const float* __restrict__ bias1, const float* __restrict__ bias2,
                       int doRelu,
                       u16* __restrict__ bOut, float* __restrict__ fOut) {
    int wid = (blockIdx.x * blockDim.x + threadIdx.x) >> 6;
    if (wid >= N_STORE) return;
    int lane = threadIdx.x & 63, slot = lane & 15, h = lane >> 4;
    int pbase = (lane & 48) << 2;
    float ald1 = b2f(alS[(size_t)wid * 16 + 8 + h]);      // ald_r1
    float ald2 = b2f(alS[(size_t)wid * 16 + 12 + h]);     // ald_r2
    int a0 = __builtin_amdgcn_readfirstlane(offs1[wid]);
    int a1e = __builtin_amdgcn_readfirstlane(offs1[wid + 1]);
    int b0 = __builtin_amdgcn_readfirstlane(offs2[wid]);
    int b1e = __builtin_amdgcn_readfirstlane(offs2[wid + 1]);
    float acc1 = 0.f, den1 = 0.f, acc2 = 0.f, den2 = 0.f;
    // r1: gather dept rows (als_r1 at alD offset 4)
    agg_seg(srcs, a0, a1e, N_DEPT, hD, alD, 4, lane, slot, h, pbase, ald1, acc1, den1);
    // r2: gather store rows (als_r2 at alS offset 4)
    agg_seg(srcs, b0, b1e, N_STORE, hS2, alS, 4, lane, slot, h, pbase, ald2, acc2, den2);
    den1 = warp16_sum(den1);
    den2 = warp16_sum(den2);
    float out = (acc1 / (den1 + 1e-16f) + bias1[lane] + acc2 / (den2 + 1e-16f) + bias2[lane]) * 0.5f;
    if (doRelu) out = out > 0.f ? out : 0.f;
    size_t oi = (size_t)wid * 64 + lane;
    if (fOut) fOut[oi] = out;
    else      bOut[oi] = f2b(out);
}

extern "C" void kernel_launch(void* const* d_in, const int* in_sizes, int n_in,
                              void* d_out, int out_size, void* d_ws, size_t ws_size,
                              hipStream_t stream) {
    const float* x_store = (const float*)d_in[0];
    const float* x_dept  = (const float*)d_in[1];
    const int* e_sd = (const int*)d_in[2];
    const int* e_ds = (const int*)d_in[3];
    const int* e_ss = (const int*)d_in[4];
    const float* W_src0  = (const float*)d_in[5];
    const float* W_dst0  = (const float*)d_in[6];
    const float* W_src_h = (const float*)d_in[7];
    const float* W_dst_h = (const float*)d_in[8];
    const float* att_src = (const float*)d_in[9];
    const float* att_dst = (const float*)d_in[10];
    const float* bias    = (const float*)d_in[11];
    const int E = in_sizes[2] / 2;

    // ---- workspace (~61 MB) ----
    char* w = (char*)d_ws;
    auto alloc = [&](size_t bytes) -> char* {
        char* p = w;
        w += (bytes + 255) & ~(size_t)255;
        return p;
    };
    int* offs_all  = (int*)alloc((size_t)(NTOT + 1) * 4);
    int* srcs_all  = (int*)alloc((size_t)3 * E * 4);
    int* bucketCnt = (int*)alloc(1024 * 4);
    int* bucketOfs = (int*)alloc(1024 * 4);
    int* bucketCur = (int*)alloc(1024 * 4);
    u16* panelS[3]; u16* panelD[3];
    for (int l = 0; l < 3; ++l) {
        int KT = (l == 0) ? 4 : 2;
        panelS[l] = (u16*)alloc((size_t)KT * 9 * 64 * 8 * 2);
        panelD[l] = (u16*)alloc((size_t)KT * 5 * 64 * 8 * 2);
    }
    u16* hS0   = (u16*)alloc((size_t)N_STORE * 64 * 2);   // h for r0 (128B rows)
    u16* hS2   = (u16*)alloc((size_t)N_STORE * 64 * 2);   // h for r2
    u16* alS   = (u16*)alloc((size_t)N_STORE * 16 * 2);   // [als0(4) als2(4) ald1(4) ald2(4)]
    u16* hD    = (u16*)alloc((size_t)N_DEPT * 64 * 2);    // h for r1
    u16* alD   = (u16*)alloc((size_t)N_DEPT * 16 * 2);    // [ald0(4) als1(4) 0(8)]
    u16* actSA = (u16*)alloc((size_t)N_STORE * 64 * 2);
    u16* actDA = (u16*)alloc((size_t)N_DEPT * 64 * 2);
    u16* actSB = actSA;                      // safe alias (stream-ordered)
    u16* actDB = actDA;
    unsigned* pairs = (unsigned*)hS0;        // 12 MB staging, dead before hS0 is written

    int* off_sd = offs_all;                      // n = N_DEPT
    int* off_ds = offs_all + N_DEPT;             // n = N_STORE
    int* off_ss = offs_all + N_DEPT + N_STORE;   // n = N_STORE

    float* outStoreF = (float*)d_out;                       // final output: f32
    float* outDeptF  = outStoreF + (size_t)N_STORE * 64;

    // ---- bucketed CSR build ----
    int ebl8 = (E + 2047) / 2048;
    k_zeroi<<<(NBUCK + 255) / 256, 256, 0, stream>>>(bucketCnt, NBUCK);
    k_bcount<<<dim3(ebl8, 3), 256, 0, stream>>>(e_sd, e_ds, e_ss, E, bucketCnt);
    k_bscan<<<1, 1024, 0, stream>>>(bucketCnt, bucketOfs, bucketCur, offs_all);
    k_bscatter<<<dim3(ebl8, 3), 256, 0, stream>>>(e_sd, e_ds, e_ss, E, bucketCur, pairs);
    k_bfinal<<<NBUCK, 256, 0, stream>>>(pairs, bucketOfs, offs_all, srcs_all);

    // ---- layers ----
    for (int l = 0; l < 3; ++l) {
        int K = (l == 0) ? 128 : 64;
        const float *Ws[3], *Wd[3], *aS[3], *aD[3];
        for (int rr = 0; rr < 3; ++rr) {
            Ws[rr] = (l == 0) ? W_src0 + (size_t)rr * 128 * 64
                              : W_src_h + (size_t)((l - 1) * 3 + rr) * 64 * 64;
            Wd[rr] = (l == 0) ? W_dst0 + (size_t)rr * 128 * 64
                              : W_dst_h + (size_t)((l - 1) * 3 + rr) * 64 * 64;
            aS[rr] = att_src + (size_t)(l * 3 + rr) * 64;
            aD[rr] = att_dst + (size_t)(l * 3 + rr) * 64;
        }
        k_pack_store<<<(K * 144 + 255) / 256, 256, 0, stream>>>(
            Ws[0], Ws[2], Wd[1], Wd[2], aS[0], aS[2], aD[1], aD[2], K, panelS[l]);
        k_pack_dept<<<(K * 80 + 255) / 256, 256, 0, stream>>>(
            Ws[1], Wd[0], aD[0], aS[1], K, panelD[l]);

        int gbS = (N_STORE / 16 * 64 + 255) / 256;
        int gbD = (N_DEPT / 16 * 64 + 255) / 256;
        if (l == 0) {
            k_gemm<4, 1, 0><<<gbS, 256, 0, stream>>>(x_store, N_STORE, K, panelS[l], hS0, hS2, alS);
            k_gemm<4, 1, 1><<<gbD, 256, 0, stream>>>(x_dept, N_DEPT, K, panelD[l], hD, nullptr, alD);
        } else if (l == 1) {
            k_gemm<2, 0, 0><<<gbS, 256, 0, stream>>>(actSA, N_STORE, K, panelS[l], hS0, hS2, alS);
            k_gemm<2, 0, 1><<<gbD, 256, 0, stream>>>(actDA, N_DEPT, K, panelD[l], hD, nullptr, alD);
        } else {
            k_gemm<2, 0, 0><<<gbS, 256, 0, stream>>>(actSB, N_STORE, K, panelS[l], hS0, hS2, alS);
            k_gemm<2, 0, 1><<<gbD, 256, 0, stream>>>(actDB, N_DEPT, K, panelD[l], hD, nullptr, alD);
        }

        int relu = (l < 2) ? 1 : 0;
        u16* bS = (l == 0) ? actSA : actSB;
        u16* bD = (l == 0) ? actDA : actDB;
        float* fS = (l == 2) ? outStoreF : nullptr;
        float* fD = (l == 2) ? outDeptF  : nullptr;
        // r0: store -> dept (final write)
        k_agg1<<<N_DEPT / 4, 256, 0, stream>>>(
            off_sd, srcs_all, hS0, alS, alD,
            bias + (size_t)(l * 3 + 0) * 64, relu, bD, fD);
        // fused r1+r2 -> store output (single write)
        k_agg2<<<N_STORE / 4, 256, 0, stream>>>(
            off_ds, srcs_all, off_ss,
            hD, alD, hS2, alS,
            bias + (size_t)(l * 3 + 1) * 64, bias + (size_t)(l * 3 + 2) * 64,
            relu, bS, fS);
    }
    (void)n_in; (void)out_size; (void)ws_size;
}